// Round 3
// 74.095 us; speedup vs baseline: 1.0250x; 1.0250x over previous
//
#include <hip/hip_runtime.h>

// RotationalConv2D R5: barrier-free K-loop WITHOUT any LDS exchange.
// Per-pixel rotation params (cos,sin,xoff,yoff) are precomputed once into a
// 1KB LDS table. In the K-loop each lane builds the exact MFMA A-fragment it
// needs (pixel 16m+col, tap tq, channels (quad&1)*8..+7) by blending directly
// from the read-only s_in tile -> A goes register->MFMA, no ds_write, no
// ordering assumptions. Split-K across waves (wave wv owns taps wv+4j),
// cross-wave f32 reduce at the end. 5 barriers total (R3 had 17).

#define KS     5
#define TILE   8
#define TW     (TILE + KS - 1)     // 12
#define CPAD   20                  // padded channel stride (floats)
#define C_IN   16
#define F_OUT  32
#define H_IN   128
#define W_IN   128
#define HO     124
#define WO     124
#define NBATCH 4
#define EPSF   1e-7f
#define BLOCK  256
#define KW     400                 // K = 25*16

// LDS layout (bytes):
//   phase 1: s_in [0,11520) | s_int [11520,12144) | s_ang [12160,13184)
//   phase 2 (epilogue, after barrier): red [0,34816) -- aliases everything
#define ANG_OFF     12160
#define RED_STRIDE  34             // floats per pixel row (136 B)
#define RED_WAVE    (64 * RED_STRIDE)
#define SMEM_BYTES  34816

typedef __attribute__((ext_vector_type(8))) short  short8;   // 8 bf16
typedef __attribute__((ext_vector_type(4))) float  floatx4;

static __device__ __forceinline__ short f2bf(float f) {
    union { float f; unsigned u; } v; v.f = f;
    unsigned r = v.u + 0x7fffu + ((v.u >> 16) & 1u);   // RNE
    return (short)(r >> 16);
}

// Blend 8 channels [ch0, ch0+8) of tap t for pixel (lxq, lyq) -> bf16 x8.
static __device__ __forceinline__ short8 blend8(
    const float* __restrict__ s_in, int lxq, int lyq,
    float co, float si, float xo, float yo, int t, int ch0)
{
    const float scl = 1.0f / (1.0f + EPSF);
    int ky = t / KS, kx = t - KS * ky;
    float sx = (co * (float)kx - si * (float)ky + xo) * scl;
    float sy = (si * (float)kx + co * (float)ky + yo) * scl;
    float fx0 = floorf(sx), fy0 = floorf(sy);
    float wx = sx - fx0, wy = sy - fy0;
    int x0 = (int)fx0, y0 = (int)fy0;
    int x1 = x0 + 1, y1 = y0 + 1;
    float vx0 = (x0 >= 0 && x0 < KS) ? 1.f : 0.f;
    float vx1 = (x1 >= 0 && x1 < KS) ? 1.f : 0.f;
    float vy0 = (y0 >= 0 && y0 < KS) ? 1.f : 0.f;
    float vy1 = (y1 >= 0 && y1 < KS) ? 1.f : 0.f;
    float w00 = (1.f - wx) * (1.f - wy) * vx0 * vy0;
    float w01 = wx * (1.f - wy) * vx1 * vy0;
    float w10 = (1.f - wx) * wy * vx0 * vy1;
    float w11 = wx * wy * vx1 * vy1;
    int cx0 = min(max(x0, 0), KS - 1), cx1 = min(max(x1, 0), KS - 1);
    int cy0 = min(max(y0, 0), KS - 1), cy1 = min(max(y1, 0), KS - 1);
    const float* p00 = &s_in[((lyq + cy0) * TW + (lxq + cx0)) * CPAD + ch0];
    const float* p01 = &s_in[((lyq + cy0) * TW + (lxq + cx1)) * CPAD + ch0];
    const float* p10 = &s_in[((lyq + cy1) * TW + (lxq + cx0)) * CPAD + ch0];
    const float* p11 = &s_in[((lyq + cy1) * TW + (lxq + cx1)) * CPAD + ch0];
    float r[8];
    #pragma unroll
    for (int cv = 0; cv < 2; ++cv) {
        float4 a = *(const float4*)(p00 + 4 * cv);
        float4 b = *(const float4*)(p01 + 4 * cv);
        float4 c = *(const float4*)(p10 + 4 * cv);
        float4 d = *(const float4*)(p11 + 4 * cv);
        r[4*cv+0] = w00 * a.x + w01 * b.x + w10 * c.x + w11 * d.x;
        r[4*cv+1] = w00 * a.y + w01 * b.y + w10 * c.y + w11 * d.y;
        r[4*cv+2] = w00 * a.z + w01 * b.z + w10 * c.z + w11 * d.z;
        r[4*cv+3] = w00 * a.w + w01 * b.w + w10 * c.w + w11 * d.w;
    }
    return (short8){f2bf(r[0]), f2bf(r[1]), f2bf(r[2]), f2bf(r[3]),
                    f2bf(r[4]), f2bf(r[5]), f2bf(r[6]), f2bf(r[7])};
}

__global__ __launch_bounds__(BLOCK, 2) void rotconv_kernel(
    const float* __restrict__ in, const float* __restrict__ Wg,
    const float* __restrict__ bg, float* __restrict__ out)
{
    __shared__ __align__(16) char smem[SMEM_BYTES];
    float*  s_in   = (float*)smem;
    float*  s_int  = (float*)(smem + 11520);
    float4* s_ang4 = (float4*)(smem + ANG_OFF);
    float*  red    = (float*)smem;             // epilogue alias

    const int tid  = threadIdx.x;
    const int bx = blockIdx.x, by = blockIdx.y, bimg = blockIdx.z;
    const int ox = bx * TILE, oy = by * TILE;

    // ---- stage input tile (12x12x16) ----
    const float* inb = in + (size_t)bimg * (H_IN * W_IN * C_IN);
    for (int i = tid; i < TW * TW * (C_IN / 4); i += BLOCK) {
        int cv = i & 3;
        int pp = i >> 2;
        int x = pp % TW, y = pp / TW;
        int gy = oy + y, gx = ox + x;
        float4 v = make_float4(0.f, 0.f, 0.f, 0.f);
        if (gy < H_IN && gx < W_IN)
            v = *(const float4*)(inb + ((size_t)(gy * W_IN + gx) * C_IN) + 4 * cv);
        *(float4*)(&s_in[pp * CPAD + 4 * cv]) = v;
    }
    __syncthreads();

    // ---- intensity = channel sum ----
    for (int pp = tid; pp < TW * TW; pp += BLOCK) {
        const float* sp = &s_in[pp * CPAD];
        float s = 0.f;
        #pragma unroll
        for (int c = 0; c < C_IN; ++c) s += sp[c];
        s_int[(pp / TW) * (TW + 1) + (pp % TW)] = s;
    }
    __syncthreads();

    // ---- per-pixel rotation params -> s_ang (threads 0..63, pixel = tid) ----
    if (tid < 64) {
        const int alx = tid & 7, aly = tid >> 3;
        float tot = EPSF, cr = 0.f, cc = 0.f;
        #pragma unroll
        for (int dy = 0; dy < KS; ++dy)
            #pragma unroll
            for (int dx = 0; dx < KS; ++dx) {
                float v = s_int[(aly + dy) * (TW + 1) + (alx + dx)];
                tot += v; cr += v * (float)dy; cc += v * (float)dx;
            }
        cr /= tot; cc /= tot;
        float ang = atan2f(cr - 2.0f, cc - 2.0f + EPSF);
        float si, co;
        sincosf(ang, &si, &co);
        float xoff = (4.0f - (co * 4.0f - si * 4.0f)) * 0.5f;
        float yoff = (4.0f - (si * 4.0f + co * 4.0f)) * 0.5f;
        s_ang4[tid] = make_float4(co, si, xoff, yoff);
    }
    __syncthreads();

    const int p    = tid & 63;     // lane
    const int wv   = tid >> 6;     // wave id 0..3
    const int col  = p & 15;       // MFMA lane&15
    const int quad = p >> 4;       // MFMA lane>>4

    // hoist per-m rotation params (pixel 16m+col) into registers
    float4 angs[4];
    #pragma unroll
    for (int m = 0; m < 4; ++m) angs[m] = s_ang4[16 * m + col];

    // ---- split-K: wave wv owns taps {wv, wv+4, ...}; step s = (wv+8s, wv+8s+4)
    floatx4 acc[4][2];
    #pragma unroll
    for (int m = 0; m < 4; ++m) {
        acc[m][0] = (floatx4){0.f, 0.f, 0.f, 0.f};
        acc[m][1] = acc[m][0];
    }

    const int nstep = (wv == 0) ? 4 : 3;       // wave 0 also covers tap 24
    const int lxq = col & 7, lyq0 = col >> 3;  // pixel 16m+col coords (lyq = 2m+lyq0)
    const int ch0 = (quad & 1) * 8;            // this lane's channel half
    const short8 zero8 = {0,0,0,0,0,0,0,0};

    #pragma unroll
    for (int s = 0; s < 4; ++s) {
        if (s < nstep) {
            const int ta = wv + 8 * s;         // < 25 whenever executed
            const int tb = ta + 4;             // >= 25 only for (wv==0, s==3)
            const int tq = (quad < 2) ? ta : tb;

            // B-fragment: lane holds B[8*quad+j][col] = W[f][tq*16 + ch0 + j]
            short8 bf0 = zero8, bf1 = zero8;
            if (tq < KS * KS) {
                const float* wp0 = Wg + (size_t)col * KW + tq * 16 + ch0;
                float4 a = *(const float4*)(wp0);
                float4 b = *(const float4*)(wp0 + 4);
                bf0 = (short8){f2bf(a.x), f2bf(a.y), f2bf(a.z), f2bf(a.w),
                               f2bf(b.x), f2bf(b.y), f2bf(b.z), f2bf(b.w)};
                const float* wp1 = wp0 + (size_t)16 * KW;
                float4 c = *(const float4*)(wp1);
                float4 d = *(const float4*)(wp1 + 4);
                bf1 = (short8){f2bf(c.x), f2bf(c.y), f2bf(c.z), f2bf(c.w),
                               f2bf(d.x), f2bf(d.y), f2bf(d.z), f2bf(d.w)};
            }

            // A-fragments built directly in registers: pixel 16m+col, tap tq,
            // channels ch0..ch0+7  (== A[col][8*quad+j] of M-tile m)
            #pragma unroll
            for (int m = 0; m < 4; ++m) {
                short8 av = zero8;
                if (tq < KS * KS)
                    av = blend8(s_in, lxq, 2 * m + lyq0,
                                angs[m].x, angs[m].y, angs[m].z, angs[m].w,
                                tq, ch0);
                acc[m][0] = __builtin_amdgcn_mfma_f32_16x16x32_bf16(av, bf0, acc[m][0], 0, 0, 0);
                acc[m][1] = __builtin_amdgcn_mfma_f32_16x16x32_bf16(av, bf1, acc[m][1], 0, 0, 0);
            }
        }
    }

    // ---- cross-wave reduce (2 barriers) ----
    __syncthreads();                           // all waves done reading s_in/s_ang
    #pragma unroll
    for (int m = 0; m < 4; ++m)
        #pragma unroll
        for (int n = 0; n < 2; ++n)
            #pragma unroll
            for (int r = 0; r < 4; ++r) {
                int px = 16 * m + 4 * quad + r;          // D: row = quad*4+reg
                red[wv * RED_WAVE + px * RED_STRIDE + n * 16 + col] = acc[m][n][r];
            }
    __syncthreads();

    // thread tid -> pixel tid>>2, f block (tid&3)*8 ; sum 4 partials + bias
    const int rpx = tid >> 2;
    const int rf0 = (tid & 3) * 8;
    float sum[8];
    #pragma unroll
    for (int j = 0; j < 8; ++j) sum[j] = bg[rf0 + j];
    #pragma unroll
    for (int w = 0; w < 4; ++w) {
        const float* rp = red + w * RED_WAVE + rpx * RED_STRIDE + rf0;
        #pragma unroll
        for (int j = 0; j < 8; ++j) sum[j] += rp[j];
    }
    const int ho = oy + (rpx >> 3), wo = ox + (rpx & 7);
    if (ho < HO && wo < WO) {
        float* op = out + (((size_t)bimg * HO + ho) * WO + wo) * F_OUT + rf0;
        *(float4*)op       = make_float4(sum[0], sum[1], sum[2], sum[3]);
        *(float4*)(op + 4) = make_float4(sum[4], sum[5], sum[6], sum[7]);
    }
}

extern "C" void kernel_launch(void* const* d_in, const int* in_sizes, int n_in,
                              void* d_out, int out_size, void* d_ws, size_t ws_size,
                              hipStream_t stream) {
    const float* in = (const float*)d_in[0];
    const float* Wg = (const float*)d_in[1];
    const float* bg = (const float*)d_in[2];
    float* out      = (float*)d_out;
    dim3 grid((WO + TILE - 1) / TILE, (HO + TILE - 1) / TILE, NBATCH);
    rotconv_kernel<<<grid, dim3(BLOCK), 0, stream>>>(in, Wg, bg, out);
}